// Round 16
// baseline (316.294 us; speedup 1.0000x reference)
//
#include <hip/hip_runtime.h>
#include <math.h>

typedef _Float16 h8f16 __attribute__((ext_vector_type(8)));
typedef _Float16 h2f16 __attribute__((ext_vector_type(2)));
typedef float f32x4 __attribute__((ext_vector_type(4)));

#define MFMA16(a, b, c) __builtin_amdgcn_mfma_f32_16x16x32_f16((a), (b), (c), 0, 0, 0)

__device__ __forceinline__ float silu_f(float v) {
    return v * __builtin_amdgcn_rcpf(1.0f + __expf(-v));
}

// Bare barrier: writer-side LDS completion + s_barrier, NO vmcnt drain.
__device__ __forceinline__ void bar_lds() {
    asm volatile("s_waitcnt lgkmcnt(0)" ::: "memory");
    __builtin_amdgcn_s_barrier();
    __builtin_amdgcn_sched_barrier(0);
}

// ---------------------------------------------------------------------------
// FAT kernel, 232 blocks x 512 threads (round-14 proven, verbatim):
//   blocks 0..127   : ODE mega-kernel (v6 — 258 us)
//   blocks 128..231 : pure-STREAMING filler: hcat x_t cols, temb cols,
//                     fw1/fw2/fw3 f32->f16 conversion (~42 MB). Hides fully.
// ---------------------------------------------------------------------------
__global__ __launch_bounds__(512, 1) void fat_kernel(
    const float* __restrict__ past,
    const float* __restrict__ xproj_w, const float* __restrict__ xproj_b,
    const float* __restrict__ z0_w, const float* __restrict__ z0_b,
    const float* __restrict__ ln_g, const float* __restrict__ ln_b,
    const float* __restrict__ w1, const float* __restrict__ b1,
    const float* __restrict__ w2, const float* __restrict__ b2,
    const float* __restrict__ w3, const float* __restrict__ b3,
    const float* __restrict__ x_t, const int* __restrict__ tvals,
    const float* __restrict__ fw1, const float* __restrict__ fw2,
    const float* __restrict__ fw3,
    float* __restrict__ zbuf, _Float16* __restrict__ hcat,
    _Float16* __restrict__ fw1h, _Float16* __restrict__ fw2h,
    _Float16* __restrict__ fw3h)
{
    __shared__ _Float16 hbuf[16][136];
    __shared__ _Float16 h1S[16][136];
    __shared__ _Float16 h2S[16][136];
    __shared__ float    pS[16][33];
    __shared__ float    x0S[16][128];
    __shared__ float    zS0[16][129];

    const int tid = threadIdx.x;

    if (blockIdx.x >= 128) {
        const int fid = blockIdx.x - 128;          // 0..103
        for (long c = fid * 512 + tid; c < 1032192; c += 104 * 512) {
            if (c < 786432) {
                const long b = c / 384, q = (c % 384) * 8;
                const float* s = x_t + b * 3072 + q;
                const f32x4 u0 = *(const f32x4*)s;
                const f32x4 u1 = *(const f32x4*)(s + 4);
                h8f16 v;
#pragma unroll
                for (int j = 0; j < 4; ++j) { v[j] = (_Float16)u0[j]; v[4 + j] = (_Float16)u1[j]; }
                *(h8f16*)&hcat[b * 3328 + q] = v;
            } else if (c < 819200) {
                const long u = c - 786432;
                const long b = u >> 4;
                const int j0 = (int)(u & 15) * 8;
                const float tv = (float)tvals[b];
                h8f16 v;
#pragma unroll
                for (int j = 0; j < 8; ++j) {
                    const int jj  = j0 + j;
                    const int idx = (jj < 64) ? jj : jj - 64;
                    const float fr = expf(-9.210340371976184f * (float)idx * (1.0f / 63.0f));
                    const float a  = tv * fr;
                    v[j] = (_Float16)((jj < 64) ? sinf(a) : cosf(a));
                }
                *(h8f16*)&hcat[b * 3328 + 3200 + j0] = v;
            } else {
                const float* src; _Float16* dst; long off;
                if (c < 925696)      { src = fw1; dst = fw1h; off = (c - 819200) * 8; }
                else if (c < 933888) { src = fw2; dst = fw2h; off = (c - 925696) * 8; }
                else                 { src = fw3; dst = fw3h; off = (c - 933888) * 8; }
                const f32x4 u0 = *(const f32x4*)(src + off);
                const f32x4 u1 = *(const f32x4*)(src + off + 4);
                h8f16 v;
#pragma unroll
                for (int j = 0; j < 4; ++j) { v[j] = (_Float16)u0[j]; v[4 + j] = (_Float16)u1[j]; }
                *(h8f16*)&dst[off] = v;
            }
        }
        return;
    }

    // ===================== ODE path (v6, verbatim) =====================
    const int wid  = tid >> 6;
    const int lane = tid & 63;
    const int lrow = lane & 15;
    const int lhi  = lane >> 4;
    const int b0   = blockIdx.x * 16;
    const int nc   = wid * 16 + lrow;
    const int koff = lhi * 8;

    h8f16 w1f[4], wcf, w2f[4], w3f[4];
    float b1t, b2r, b3r;
    {
#pragma unroll
        for (int ks = 0; ks < 4; ++ks) {
            h8f16 v1, v2, v3;
#pragma unroll
            for (int j = 0; j < 8; ++j) {
                const int k = ks * 32 + koff + j;
                v1[j] = (_Float16)(w1[nc * 256 + k] * ln_g[k]);
                v2[j] = (_Float16)w2[nc * 128 + k];
                v3[j] = (_Float16)w3[nc * 128 + k];
            }
            w1f[ks] = v1; w2f[ks] = v2; w3f[ks] = v3;
        }
        float wc[8] = {0, 0, 0, 0, 0, 0, 0, 0};
        float bc = 0.0f, bb = 0.0f;
        const float* w1a = w1 + nc * 256;
        const float* w1b = w1a + 128;
#pragma unroll 4
        for (int k = 0; k < 128; ++k) {
            const float a = w1b[k];
            bc += a * xproj_b[k];
            bb += w1a[k] * ln_b[k];
            const float* xr = xproj_w + k * 32 + koff;
#pragma unroll
            for (int j = 0; j < 8; ++j) wc[j] += a * xr[j];
        }
        h8f16 v;
#pragma unroll
        for (int j = 0; j < 8; ++j) v[j] = (_Float16)wc[j];
        wcf = v;
        b1t = b1[nc] + bc + bb;
        b2r = b2[nc]; b3r = b3[nc];
    }

    pS[tid >> 5][tid & 31] = past[(long)(b0 + (tid >> 5)) * 16384 + (tid & 31)];
    __syncthreads();
    {
        const int r  = tid >> 5;
        const int c0 = (tid & 31) * 4;
#pragma unroll
        for (int cc = 0; cc < 4; ++cc) {
            const int kc = c0 + cc;
            float s = xproj_b[kc];
            const float* xr = xproj_w + kc * 32;
#pragma unroll
            for (int c = 0; c < 32; ++c) s += pS[r][c] * xr[c];
            x0S[r][kc] = s;
        }
    }
    __syncthreads();
    {
        const int nn = tid & 127;
        const int r0 = (tid >> 7) * 4;
        for (int p = 0; p < 4; ++p) {
            const int r = r0 + p;
            float s = z0_b[nn];
            const float* zr = z0_w + nn * 128;
            for (int k = 0; k < 128; ++k) s += x0S[r][k] * zr[k];
            zS0[r][nn] = s;
        }
    }
    __syncthreads();

    float zc[4], krk[4];
#pragma unroll
    for (int j = 0; j < 4; ++j) {
        zc[j] = zS0[4 * lhi + j][nc];
        hbuf[4 * lhi + j][nc] = (_Float16)zc[j];
    }

    const float DT = 1.0f / 32.0f;

    f32x4 s0a, s0b, s1a, s1b;
    auto stage = [&](int e) {
        const float pos = (float)e * 7.984375f;   // e*(511/64), exact
        const int i0 = (int)pos;
        const int i1 = (i0 < 511) ? i0 + 1 : 511;
        const float* base = past + (long)(b0 + lrow) * 16384;
        const float* p0 = base + i0 * 32 + koff;
        const float* p1 = base + i1 * 32 + koff;
        s0a = *(const f32x4*)p0; s0b = *(const f32x4*)(p0 + 4);
        s1a = *(const f32x4*)p1; s1b = *(const f32x4*)(p1 + 4);
    };
    auto blend = [&](int e) -> h8f16 {
        const float pos = (float)e * 7.984375f;
        const float w = pos - floorf(pos);
        h8f16 r;
#pragma unroll
        for (int j = 0; j < 4; ++j) {
            r[j]     = (_Float16)(s0a[j] + w * (s1a[j] - s0a[j]));
            r[4 + j] = (_Float16)(s0b[j] + w * (s1b[j] - s0b[j]));
        }
        return r;
    };

    const h2f16 one2 = {(_Float16)1.0f, (_Float16)1.0f};

    auto phaseA = [&](h8f16 bxc) {
        h8f16 xf[4];
#pragma unroll
        for (int ks = 0; ks < 4; ++ks)
            xf[ks] = *(const h8f16*)&hbuf[lrow][ks * 32 + koff];
        float s0 = 0.f, s1 = 0.f, q0 = 0.f, q1 = 0.f;
#pragma unroll
        for (int ks = 0; ks < 4; ++ks) {
#pragma unroll
            for (int p = 0; p < 4; ++p) {
                const h2f16 x2 = {xf[ks][2 * p], xf[ks][2 * p + 1]};
                if (p & 1) {
                    s1 = __builtin_amdgcn_fdot2(x2, one2, s1, false);
                    q1 = __builtin_amdgcn_fdot2(x2, x2, q1, false);
                } else {
                    s0 = __builtin_amdgcn_fdot2(x2, one2, s0, false);
                    q0 = __builtin_amdgcn_fdot2(x2, x2, q0, false);
                }
            }
        }
        float s = s0 + s1, q = q0 + q1;
        s += __shfl_xor(s, 16); q += __shfl_xor(q, 16);
        s += __shfl_xor(s, 32); q += __shfl_xor(q, 32);
        const float mu  = s * (1.0f / 128.0f);
        const float var = q * (1.0f / 128.0f) - mu * mu;
        const float inv = 1.0f / sqrtf(var + 1e-5f);
        const _Float16 ih = (_Float16)inv;
        const _Float16 mh = (_Float16)(-mu * inv);
        h8f16 ip, mp;
#pragma unroll
        for (int j = 0; j < 8; ++j) { ip[j] = ih; mp[j] = mh; }
        f32x4 acc = {0, 0, 0, 0};
#pragma unroll
        for (int ks = 0; ks < 4; ++ks) {
            const h8f16 az = xf[ks] * ip + mp;
            acc = MFMA16(az, w1f[ks], acc);
        }
        acc = MFMA16(bxc, wcf, acc);
#pragma unroll
        for (int j = 0; j < 4; ++j)
            h1S[4 * lhi + j][nc] = (_Float16)silu_f(acc[j] + b1t);
    };
    auto phaseB = [&]() {
        f32x4 acc = {0, 0, 0, 0};
#pragma unroll
        for (int ks = 0; ks < 4; ++ks) {
            const h8f16 a = *(const h8f16*)&h1S[lrow][ks * 32 + koff];
            acc = MFMA16(a, w2f[ks], acc);
        }
#pragma unroll
        for (int j = 0; j < 4; ++j)
            h2S[4 * lhi + j][nc] = (_Float16)silu_f(acc[j] + b2r);
    };
    auto phaseC = [&]() -> f32x4 {
        f32x4 acc = {0, 0, 0, 0};
#pragma unroll
        for (int ks = 0; ks < 4; ++ks) {
            const h8f16 a = *(const h8f16*)&h2S[lrow][ks * 32 + koff];
            acc = MFMA16(a, w3f[ks], acc);
        }
#pragma unroll
        for (int j = 0; j < 4; ++j) acc[j] += b3r;
        return acc;
    };

    stage(0);
    h8f16 bxc = blend(0);
    __syncthreads();

#pragma unroll 1
    for (int st = 0; st < 32; ++st) {
        const int e1 = 2 * st + 1, e2 = 2 * st + 2;
        phaseA(bxc);
        stage(e1);
        bar_lds();
        phaseB(); bar_lds();
        {
            const f32x4 k = phaseC();
#pragma unroll
            for (int j = 0; j < 4; ++j) {
                krk[j] = k[j];
                hbuf[4 * lhi + j][nc] = (_Float16)(zc[j] + 0.5f * DT * k[j]);
            }
        }
        bar_lds();
        bxc = blend(e1);
        phaseA(bxc); bar_lds();
        phaseB(); bar_lds();
        {
            const f32x4 k = phaseC();
#pragma unroll
            for (int j = 0; j < 4; ++j) {
                krk[j] += 2.0f * k[j];
                hbuf[4 * lhi + j][nc] = (_Float16)(zc[j] + 0.5f * DT * k[j]);
            }
        }
        bar_lds();
        phaseA(bxc);
        stage(e2);
        bar_lds();
        phaseB(); bar_lds();
        {
            const f32x4 k = phaseC();
#pragma unroll
            for (int j = 0; j < 4; ++j) {
                krk[j] += 2.0f * k[j];
                hbuf[4 * lhi + j][nc] = (_Float16)(zc[j] + DT * k[j]);
            }
        }
        bar_lds();
        bxc = blend(e2);
        phaseA(bxc); bar_lds();
        phaseB(); bar_lds();
        {
            const f32x4 k = phaseC();
#pragma unroll
            for (int j = 0; j < 4; ++j) {
                zc[j] += (DT / 6.0f) * (krk[j] + k[j]);
                hbuf[4 * lhi + j][nc] = (_Float16)zc[j];
            }
        }
        bar_lds();
    }

#pragma unroll
    for (int j = 0; j < 4; ++j)
        zbuf[(long)(b0 + 4 * lhi + j) * 128 + nc] = zc[j];
}

// ---------------------------------------------------------------------------
// gemm1n: h1 = silu([hcat_xt | cond(zbuf,f32) | hcat_temb] @ fw1h.T + fb1)
// Tile 64(M) x 128(N), K=3328 -> hcat re-read halved vs 64x64.
// grid (32, 2) x 256 threads. Values bitwise-identical to round-14 gemm1z.
// ---------------------------------------------------------------------------
__global__ __launch_bounds__(256) void gemm1n_kernel(
    const _Float16* __restrict__ hcat, const float* __restrict__ cond,
    const _Float16* __restrict__ fw1h, const float* __restrict__ fb1,
    _Float16* __restrict__ h1)
{
    __shared__ _Float16 aS[64][40];
    __shared__ _Float16 wS[128][40];
    const int mb = blockIdx.x * 64, nb = blockIdx.y * 128;
    const int tid = threadIdx.x, lane = tid & 63, wq = tid >> 6;
    const int lrow = lane & 15, lhi = lane >> 4;
    f32x4 acc[8];
#pragma unroll
    for (int nt = 0; nt < 8; ++nt) acc[nt] = (f32x4){0, 0, 0, 0};

    const int sr  = tid >> 2;          // A staging: 64 rows x 32 (8/thread)
    const int sk  = (tid & 3) * 8;
    const int sr2 = tid >> 1;          // W staging: 128 rows x 32 (16/thread)
    const int sk2 = (tid & 1) * 16;

    for (int k0 = 0; k0 < 3328; k0 += 32) {
        if (k0 >= 3072 && k0 < 3200) {
            const float* s = cond + (long)(mb + sr) * 128 + (k0 - 3072) + sk;
            const f32x4 u0 = *(const f32x4*)s;
            const f32x4 u1 = *(const f32x4*)(s + 4);
            h8f16 v;
#pragma unroll
            for (int j = 0; j < 4; ++j) { v[j] = (_Float16)u0[j]; v[4 + j] = (_Float16)u1[j]; }
            *(h8f16*)&aS[sr][sk] = v;
        } else {
            *(h8f16*)&aS[sr][sk] =
                *(const h8f16*)&hcat[(long)(mb + sr) * 3328 + k0 + sk];
        }
        *(h8f16*)&wS[sr2][sk2] =
            *(const h8f16*)&fw1h[(long)(nb + sr2) * 3328 + k0 + sk2];
        *(h8f16*)&wS[sr2][sk2 + 8] =
            *(const h8f16*)&fw1h[(long)(nb + sr2) * 3328 + k0 + sk2 + 8];
        __syncthreads();
        const h8f16 a = *(const h8f16*)&aS[wq * 16 + lrow][lhi * 8];
#pragma unroll
        for (int nt = 0; nt < 8; ++nt) {
            const h8f16 bfr = *(const h8f16*)&wS[nt * 16 + lrow][lhi * 8];
            acc[nt] = MFMA16(a, bfr, acc[nt]);
        }
        __syncthreads();
    }

#pragma unroll
    for (int nt = 0; nt < 8; ++nt) {
        const int cc = nb + nt * 16 + lrow;
        const float bv = fb1[cc];
#pragma unroll
        for (int j = 0; j < 4; ++j) {
            const int rr = mb + wq * 16 + lhi * 4 + j;
            h1[(long)rr * 256 + cc] = (_Float16)silu_f(acc[nt][j] + bv);
        }
    }
}

// ---------------------------------------------------------------------------
// Generic all-f16 MFMA GEMM: out(M,N) = [silu](A(M,K) @ W(N,K).T + bias)
// ---------------------------------------------------------------------------
template <bool SILU, bool OUT_F16>
__global__ __launch_bounds__(256) void gemm_ff(
    const _Float16* __restrict__ A, const _Float16* __restrict__ W,
    const float* __restrict__ bias, void* __restrict__ out,
    int M, int N, int K)
{
    __shared__ _Float16 aS[64][40];
    __shared__ _Float16 wS[64][40];
    const int mb = blockIdx.x * 64, nb = blockIdx.y * 64;
    const int tid = threadIdx.x, lane = tid & 63, wq = tid >> 6;
    const int lrow = lane & 15, lhi = lane >> 4;
    f32x4 acc[4];
#pragma unroll
    for (int nt = 0; nt < 4; ++nt) acc[nt] = (f32x4){0, 0, 0, 0};

    const int sr = tid >> 2;
    const int sk = (tid & 3) * 8;

    for (int k0 = 0; k0 < K; k0 += 32) {
        *(h8f16*)&aS[sr][sk] = *(const h8f16*)&A[(long)(mb + sr) * K + k0 + sk];
        *(h8f16*)&wS[sr][sk] = *(const h8f16*)&W[(long)(nb + sr) * K + k0 + sk];
        __syncthreads();
        const h8f16 a = *(const h8f16*)&aS[wq * 16 + lrow][lhi * 8];
#pragma unroll
        for (int nt = 0; nt < 4; ++nt) {
            const h8f16 bfr = *(const h8f16*)&wS[nt * 16 + lrow][lhi * 8];
            acc[nt] = MFMA16(a, bfr, acc[nt]);
        }
        __syncthreads();
    }

#pragma unroll
    for (int nt = 0; nt < 4; ++nt) {
        const int cc = nb + nt * 16 + lrow;
        const float bv = bias[cc];
#pragma unroll
        for (int j = 0; j < 4; ++j) {
            const int rr = mb + wq * 16 + lhi * 4 + j;
            float v = acc[nt][j] + bv;
            if (SILU) v = silu_f(v);
            if (OUT_F16) ((_Float16*)out)[(long)rr * N + cc] = (_Float16)v;
            else         ((float*)out)[(long)rr * N + cc] = v;
        }
    }
}

// ---------------------------------------------------------------------------
extern "C" void kernel_launch(void* const* d_in, const int* in_sizes, int n_in,
                              void* d_out, int out_size, void* d_ws, size_t ws_size,
                              hipStream_t stream)
{
    const float* x_t     = (const float*)d_in[0];
    const float* past    = (const float*)d_in[1];
    const int*   tvals   = (const int*)d_in[2];
    const float* xproj_w = (const float*)d_in[3];
    const float* xproj_b = (const float*)d_in[4];
    const float* z0_w    = (const float*)d_in[5];
    const float* z0_b    = (const float*)d_in[6];
    const float* ln_g    = (const float*)d_in[7];
    const float* ln_b    = (const float*)d_in[8];
    const float* w1      = (const float*)d_in[9];
    const float* b1      = (const float*)d_in[10];
    const float* w2      = (const float*)d_in[11];
    const float* b2      = (const float*)d_in[12];
    const float* w3      = (const float*)d_in[13];
    const float* b3      = (const float*)d_in[14];
    const float* fw1     = (const float*)d_in[15];
    const float* fb1     = (const float*)d_in[16];
    const float* fw2     = (const float*)d_in[17];
    const float* fb2     = (const float*)d_in[18];
    const float* fw3     = (const float*)d_in[19];
    const float* fb3     = (const float*)d_in[20];

    char* ws = (char*)d_ws;
    float*     zbuf = (float*)ws;                         // 1 MB   (B*128 f32)
    _Float16*  hcat = (_Float16*)(ws + (1 << 20));        // 13.63 MB
    _Float16*  h1   = (_Float16*)(ws + 15 * (1 << 20));   // 1 MB
    _Float16*  h2   = (_Float16*)(ws + 16 * (1 << 20));   // 1 MB
    _Float16*  fw1h = (_Float16*)(ws + 17 * (1 << 20));   // 1.70 MB (256x3328)
    _Float16*  fw2h = (_Float16*)(ws + 19 * (1 << 20));   // 0.13 MB (256x256)
    _Float16*  fw3h = (_Float16*)(ws + 20 * (1 << 20));   // 1.57 MB (3072x256)

    fat_kernel<<<232, 512, 0, stream>>>(past, xproj_w, xproj_b, z0_w, z0_b,
                                        ln_g, ln_b, w1, b1, w2, b2, w3, b3,
                                        x_t, tvals, fw1, fw2, fw3,
                                        zbuf, hcat, fw1h, fw2h, fw3h);

    gemm1n_kernel<<<dim3(32, 2), 256, 0, stream>>>(hcat, zbuf, fw1h, fb1, h1);

    gemm_ff<true,  true ><<<dim3(32, 4),  256, 0, stream>>>(h1, fw2h, fb2, h2, 2048, 256, 256);
    gemm_ff<false, false><<<dim3(32, 48), 256, 0, stream>>>(h2, fw3h, fb3, d_out, 2048, 3072, 256);
}

// Round 17
// 297.486 us; speedup vs baseline: 1.0632x; 1.0632x over previous
//
#include <hip/hip_runtime.h>
#include <math.h>

typedef _Float16 h8f16 __attribute__((ext_vector_type(8)));
typedef _Float16 h2f16 __attribute__((ext_vector_type(2)));
typedef float f32x4 __attribute__((ext_vector_type(4)));

#define MFMA16(a, b, c) __builtin_amdgcn_mfma_f32_16x16x32_f16((a), (b), (c), 0, 0, 0)

__device__ __forceinline__ float silu_f(float v) {
    return v * __builtin_amdgcn_rcpf(1.0f + __expf(-v));
}

// Bare barrier: writer-side LDS completion + s_barrier, NO vmcnt drain.
__device__ __forceinline__ void bar_lds() {
    asm volatile("s_waitcnt lgkmcnt(0)" ::: "memory");
    __builtin_amdgcn_s_barrier();
    __builtin_amdgcn_sched_barrier(0);
}

// ---------------------------------------------------------------------------
// FAT kernel, 232 blocks x 512 threads (round-14 proven, verbatim):
//   blocks 0..127   : ODE mega-kernel (v6 — 258 us)
//   blocks 128..231 : pure-STREAMING filler: hcat x_t cols, temb cols,
//                     fw1/fw2/fw3 f32->f16 conversion (~42 MB). Hides fully.
// ---------------------------------------------------------------------------
__global__ __launch_bounds__(512, 1) void fat_kernel(
    const float* __restrict__ past,
    const float* __restrict__ xproj_w, const float* __restrict__ xproj_b,
    const float* __restrict__ z0_w, const float* __restrict__ z0_b,
    const float* __restrict__ ln_g, const float* __restrict__ ln_b,
    const float* __restrict__ w1, const float* __restrict__ b1,
    const float* __restrict__ w2, const float* __restrict__ b2,
    const float* __restrict__ w3, const float* __restrict__ b3,
    const float* __restrict__ x_t, const int* __restrict__ tvals,
    const float* __restrict__ fw1, const float* __restrict__ fw2,
    const float* __restrict__ fw3,
    float* __restrict__ zbuf, _Float16* __restrict__ hcat,
    _Float16* __restrict__ fw1h, _Float16* __restrict__ fw2h,
    _Float16* __restrict__ fw3h)
{
    __shared__ _Float16 hbuf[16][136];
    __shared__ _Float16 h1S[16][136];
    __shared__ _Float16 h2S[16][136];
    __shared__ float    pS[16][33];
    __shared__ float    x0S[16][128];
    __shared__ float    zS0[16][129];

    const int tid = threadIdx.x;

    if (blockIdx.x >= 128) {
        const int fid = blockIdx.x - 128;          // 0..103
        for (long c = fid * 512 + tid; c < 1032192; c += 104 * 512) {
            if (c < 786432) {
                const long b = c / 384, q = (c % 384) * 8;
                const float* s = x_t + b * 3072 + q;
                const f32x4 u0 = *(const f32x4*)s;
                const f32x4 u1 = *(const f32x4*)(s + 4);
                h8f16 v;
#pragma unroll
                for (int j = 0; j < 4; ++j) { v[j] = (_Float16)u0[j]; v[4 + j] = (_Float16)u1[j]; }
                *(h8f16*)&hcat[b * 3328 + q] = v;
            } else if (c < 819200) {
                const long u = c - 786432;
                const long b = u >> 4;
                const int j0 = (int)(u & 15) * 8;
                const float tv = (float)tvals[b];
                h8f16 v;
#pragma unroll
                for (int j = 0; j < 8; ++j) {
                    const int jj  = j0 + j;
                    const int idx = (jj < 64) ? jj : jj - 64;
                    const float fr = expf(-9.210340371976184f * (float)idx * (1.0f / 63.0f));
                    const float a  = tv * fr;
                    v[j] = (_Float16)((jj < 64) ? sinf(a) : cosf(a));
                }
                *(h8f16*)&hcat[b * 3328 + 3200 + j0] = v;
            } else {
                const float* src; _Float16* dst; long off;
                if (c < 925696)      { src = fw1; dst = fw1h; off = (c - 819200) * 8; }
                else if (c < 933888) { src = fw2; dst = fw2h; off = (c - 925696) * 8; }
                else                 { src = fw3; dst = fw3h; off = (c - 933888) * 8; }
                const f32x4 u0 = *(const f32x4*)(src + off);
                const f32x4 u1 = *(const f32x4*)(src + off + 4);
                h8f16 v;
#pragma unroll
                for (int j = 0; j < 4; ++j) { v[j] = (_Float16)u0[j]; v[4 + j] = (_Float16)u1[j]; }
                *(h8f16*)&dst[off] = v;
            }
        }
        return;
    }

    // ===================== ODE path (v6, verbatim) =====================
    const int wid  = tid >> 6;
    const int lane = tid & 63;
    const int lrow = lane & 15;
    const int lhi  = lane >> 4;
    const int b0   = blockIdx.x * 16;
    const int nc   = wid * 16 + lrow;
    const int koff = lhi * 8;

    h8f16 w1f[4], wcf, w2f[4], w3f[4];
    float b1t, b2r, b3r;
    {
#pragma unroll
        for (int ks = 0; ks < 4; ++ks) {
            h8f16 v1, v2, v3;
#pragma unroll
            for (int j = 0; j < 8; ++j) {
                const int k = ks * 32 + koff + j;
                v1[j] = (_Float16)(w1[nc * 256 + k] * ln_g[k]);
                v2[j] = (_Float16)w2[nc * 128 + k];
                v3[j] = (_Float16)w3[nc * 128 + k];
            }
            w1f[ks] = v1; w2f[ks] = v2; w3f[ks] = v3;
        }
        float wc[8] = {0, 0, 0, 0, 0, 0, 0, 0};
        float bc = 0.0f, bb = 0.0f;
        const float* w1a = w1 + nc * 256;
        const float* w1b = w1a + 128;
#pragma unroll 4
        for (int k = 0; k < 128; ++k) {
            const float a = w1b[k];
            bc += a * xproj_b[k];
            bb += w1a[k] * ln_b[k];
            const float* xr = xproj_w + k * 32 + koff;
#pragma unroll
            for (int j = 0; j < 8; ++j) wc[j] += a * xr[j];
        }
        h8f16 v;
#pragma unroll
        for (int j = 0; j < 8; ++j) v[j] = (_Float16)wc[j];
        wcf = v;
        b1t = b1[nc] + bc + bb;
        b2r = b2[nc]; b3r = b3[nc];
    }

    pS[tid >> 5][tid & 31] = past[(long)(b0 + (tid >> 5)) * 16384 + (tid & 31)];
    __syncthreads();
    {
        const int r  = tid >> 5;
        const int c0 = (tid & 31) * 4;
#pragma unroll
        for (int cc = 0; cc < 4; ++cc) {
            const int kc = c0 + cc;
            float s = xproj_b[kc];
            const float* xr = xproj_w + kc * 32;
#pragma unroll
            for (int c = 0; c < 32; ++c) s += pS[r][c] * xr[c];
            x0S[r][kc] = s;
        }
    }
    __syncthreads();
    {
        const int nn = tid & 127;
        const int r0 = (tid >> 7) * 4;
        for (int p = 0; p < 4; ++p) {
            const int r = r0 + p;
            float s = z0_b[nn];
            const float* zr = z0_w + nn * 128;
            for (int k = 0; k < 128; ++k) s += x0S[r][k] * zr[k];
            zS0[r][nn] = s;
        }
    }
    __syncthreads();

    float zc[4], krk[4];
#pragma unroll
    for (int j = 0; j < 4; ++j) {
        zc[j] = zS0[4 * lhi + j][nc];
        hbuf[4 * lhi + j][nc] = (_Float16)zc[j];
    }

    const float DT = 1.0f / 32.0f;

    f32x4 s0a, s0b, s1a, s1b;
    auto stage = [&](int e) {
        const float pos = (float)e * 7.984375f;   // e*(511/64), exact
        const int i0 = (int)pos;
        const int i1 = (i0 < 511) ? i0 + 1 : 511;
        const float* base = past + (long)(b0 + lrow) * 16384;
        const float* p0 = base + i0 * 32 + koff;
        const float* p1 = base + i1 * 32 + koff;
        s0a = *(const f32x4*)p0; s0b = *(const f32x4*)(p0 + 4);
        s1a = *(const f32x4*)p1; s1b = *(const f32x4*)(p1 + 4);
    };
    auto blend = [&](int e) -> h8f16 {
        const float pos = (float)e * 7.984375f;
        const float w = pos - floorf(pos);
        h8f16 r;
#pragma unroll
        for (int j = 0; j < 4; ++j) {
            r[j]     = (_Float16)(s0a[j] + w * (s1a[j] - s0a[j]));
            r[4 + j] = (_Float16)(s0b[j] + w * (s1b[j] - s0b[j]));
        }
        return r;
    };

    const h2f16 one2 = {(_Float16)1.0f, (_Float16)1.0f};

    auto phaseA = [&](h8f16 bxc) {
        h8f16 xf[4];
#pragma unroll
        for (int ks = 0; ks < 4; ++ks)
            xf[ks] = *(const h8f16*)&hbuf[lrow][ks * 32 + koff];
        float s0 = 0.f, s1 = 0.f, q0 = 0.f, q1 = 0.f;
#pragma unroll
        for (int ks = 0; ks < 4; ++ks) {
#pragma unroll
            for (int p = 0; p < 4; ++p) {
                const h2f16 x2 = {xf[ks][2 * p], xf[ks][2 * p + 1]};
                if (p & 1) {
                    s1 = __builtin_amdgcn_fdot2(x2, one2, s1, false);
                    q1 = __builtin_amdgcn_fdot2(x2, x2, q1, false);
                } else {
                    s0 = __builtin_amdgcn_fdot2(x2, one2, s0, false);
                    q0 = __builtin_amdgcn_fdot2(x2, x2, q0, false);
                }
            }
        }
        float s = s0 + s1, q = q0 + q1;
        s += __shfl_xor(s, 16); q += __shfl_xor(q, 16);
        s += __shfl_xor(s, 32); q += __shfl_xor(q, 32);
        const float mu  = s * (1.0f / 128.0f);
        const float var = q * (1.0f / 128.0f) - mu * mu;
        const float inv = 1.0f / sqrtf(var + 1e-5f);
        const _Float16 ih = (_Float16)inv;
        const _Float16 mh = (_Float16)(-mu * inv);
        h8f16 ip, mp;
#pragma unroll
        for (int j = 0; j < 8; ++j) { ip[j] = ih; mp[j] = mh; }
        f32x4 acc = {0, 0, 0, 0};
#pragma unroll
        for (int ks = 0; ks < 4; ++ks) {
            const h8f16 az = xf[ks] * ip + mp;
            acc = MFMA16(az, w1f[ks], acc);
        }
        acc = MFMA16(bxc, wcf, acc);
#pragma unroll
        for (int j = 0; j < 4; ++j)
            h1S[4 * lhi + j][nc] = (_Float16)silu_f(acc[j] + b1t);
    };
    auto phaseB = [&]() {
        f32x4 acc = {0, 0, 0, 0};
#pragma unroll
        for (int ks = 0; ks < 4; ++ks) {
            const h8f16 a = *(const h8f16*)&h1S[lrow][ks * 32 + koff];
            acc = MFMA16(a, w2f[ks], acc);
        }
#pragma unroll
        for (int j = 0; j < 4; ++j)
            h2S[4 * lhi + j][nc] = (_Float16)silu_f(acc[j] + b2r);
    };
    auto phaseC = [&]() -> f32x4 {
        f32x4 acc = {0, 0, 0, 0};
#pragma unroll
        for (int ks = 0; ks < 4; ++ks) {
            const h8f16 a = *(const h8f16*)&h2S[lrow][ks * 32 + koff];
            acc = MFMA16(a, w3f[ks], acc);
        }
#pragma unroll
        for (int j = 0; j < 4; ++j) acc[j] += b3r;
        return acc;
    };

    stage(0);
    h8f16 bxc = blend(0);
    __syncthreads();

#pragma unroll 1
    for (int st = 0; st < 32; ++st) {
        const int e1 = 2 * st + 1, e2 = 2 * st + 2;
        phaseA(bxc);
        stage(e1);
        bar_lds();
        phaseB(); bar_lds();
        {
            const f32x4 k = phaseC();
#pragma unroll
            for (int j = 0; j < 4; ++j) {
                krk[j] = k[j];
                hbuf[4 * lhi + j][nc] = (_Float16)(zc[j] + 0.5f * DT * k[j]);
            }
        }
        bar_lds();
        bxc = blend(e1);
        phaseA(bxc); bar_lds();
        phaseB(); bar_lds();
        {
            const f32x4 k = phaseC();
#pragma unroll
            for (int j = 0; j < 4; ++j) {
                krk[j] += 2.0f * k[j];
                hbuf[4 * lhi + j][nc] = (_Float16)(zc[j] + 0.5f * DT * k[j]);
            }
        }
        bar_lds();
        phaseA(bxc);
        stage(e2);
        bar_lds();
        phaseB(); bar_lds();
        {
            const f32x4 k = phaseC();
#pragma unroll
            for (int j = 0; j < 4; ++j) {
                krk[j] += 2.0f * k[j];
                hbuf[4 * lhi + j][nc] = (_Float16)(zc[j] + DT * k[j]);
            }
        }
        bar_lds();
        bxc = blend(e2);
        phaseA(bxc); bar_lds();
        phaseB(); bar_lds();
        {
            const f32x4 k = phaseC();
#pragma unroll
            for (int j = 0; j < 4; ++j) {
                zc[j] += (DT / 6.0f) * (krk[j] + k[j]);
                hbuf[4 * lhi + j][nc] = (_Float16)zc[j];
            }
        }
        bar_lds();
    }

#pragma unroll
    for (int j = 0; j < 4; ++j)
        zbuf[(long)(b0 + 4 * lhi + j) * 128 + nc] = zc[j];
}

// ---------------------------------------------------------------------------
// gemm1z: h1 = silu([hcat_xt | cond(zbuf,f32) | hcat_temb] @ fw1h.T + fb1)
// (round-14 proven, verbatim — 128 blocks, 64x64 tile)
// ---------------------------------------------------------------------------
__global__ __launch_bounds__(256) void gemm1z_kernel(
    const _Float16* __restrict__ hcat, const float* __restrict__ cond,
    const _Float16* __restrict__ fw1h, const float* __restrict__ fb1,
    _Float16* __restrict__ h1)
{
    __shared__ _Float16 aS[64][40];
    __shared__ _Float16 wS[64][40];
    const int mb = blockIdx.x * 64, nb = blockIdx.y * 64;
    const int tid = threadIdx.x, lane = tid & 63, wq = tid >> 6;
    const int lrow = lane & 15, lhi = lane >> 4;
    f32x4 acc[4];
#pragma unroll
    for (int nt = 0; nt < 4; ++nt) acc[nt] = (f32x4){0, 0, 0, 0};

    const int sr = tid >> 2;
    const int sk = (tid & 3) * 8;

    for (int k0 = 0; k0 < 3328; k0 += 32) {
        if (k0 >= 3072 && k0 < 3200) {
            const float* s = cond + (long)(mb + sr) * 128 + (k0 - 3072) + sk;
            const f32x4 u0 = *(const f32x4*)s;
            const f32x4 u1 = *(const f32x4*)(s + 4);
            h8f16 v;
#pragma unroll
            for (int j = 0; j < 4; ++j) { v[j] = (_Float16)u0[j]; v[4 + j] = (_Float16)u1[j]; }
            *(h8f16*)&aS[sr][sk] = v;
        } else {
            *(h8f16*)&aS[sr][sk] =
                *(const h8f16*)&hcat[(long)(mb + sr) * 3328 + k0 + sk];
        }
        *(h8f16*)&wS[sr][sk] = *(const h8f16*)&fw1h[(long)(nb + sr) * 3328 + k0 + sk];
        __syncthreads();
        const h8f16 a = *(const h8f16*)&aS[wq * 16 + lrow][lhi * 8];
#pragma unroll
        for (int nt = 0; nt < 4; ++nt) {
            const h8f16 bfr = *(const h8f16*)&wS[nt * 16 + lrow][lhi * 8];
            acc[nt] = MFMA16(a, bfr, acc[nt]);
        }
        __syncthreads();
    }

#pragma unroll
    for (int nt = 0; nt < 4; ++nt) {
        const int cc = nb + nt * 16 + lrow;
        const float bv = fb1[cc];
#pragma unroll
        for (int j = 0; j < 4; ++j) {
            const int rr = mb + wq * 16 + lhi * 4 + j;
            h1[(long)rr * 256 + cc] = (_Float16)silu_f(acc[nt][j] + bv);
        }
    }
}

// ---------------------------------------------------------------------------
// Generic all-f16 MFMA GEMM (64x64): out = [silu](A @ W.T + bias)
// ---------------------------------------------------------------------------
template <bool SILU, bool OUT_F16>
__global__ __launch_bounds__(256) void gemm_ff(
    const _Float16* __restrict__ A, const _Float16* __restrict__ W,
    const float* __restrict__ bias, void* __restrict__ out,
    int M, int N, int K)
{
    __shared__ _Float16 aS[64][40];
    __shared__ _Float16 wS[64][40];
    const int mb = blockIdx.x * 64, nb = blockIdx.y * 64;
    const int tid = threadIdx.x, lane = tid & 63, wq = tid >> 6;
    const int lrow = lane & 15, lhi = lane >> 4;
    f32x4 acc[4];
#pragma unroll
    for (int nt = 0; nt < 4; ++nt) acc[nt] = (f32x4){0, 0, 0, 0};

    const int sr = tid >> 2;
    const int sk = (tid & 3) * 8;

    for (int k0 = 0; k0 < K; k0 += 32) {
        *(h8f16*)&aS[sr][sk] = *(const h8f16*)&A[(long)(mb + sr) * K + k0 + sk];
        *(h8f16*)&wS[sr][sk] = *(const h8f16*)&W[(long)(nb + sr) * K + k0 + sk];
        __syncthreads();
        const h8f16 a = *(const h8f16*)&aS[wq * 16 + lrow][lhi * 8];
#pragma unroll
        for (int nt = 0; nt < 4; ++nt) {
            const h8f16 bfr = *(const h8f16*)&wS[nt * 16 + lrow][lhi * 8];
            acc[nt] = MFMA16(a, bfr, acc[nt]);
        }
        __syncthreads();
    }

#pragma unroll
    for (int nt = 0; nt < 4; ++nt) {
        const int cc = nb + nt * 16 + lrow;
        const float bv = bias[cc];
#pragma unroll
        for (int j = 0; j < 4; ++j) {
            const int rr = mb + wq * 16 + lhi * 4 + j;
            float v = acc[nt][j] + bv;
            if (SILU) v = silu_f(v);
            if (OUT_F16) ((_Float16*)out)[(long)rr * N + cc] = (_Float16)v;
            else         ((float*)out)[(long)rr * N + cc] = v;
        }
    }
}

// ---------------------------------------------------------------------------
// gemm3w: out = h2 @ fw3h.T + fb3, tile 64(M) x 128(N), K=256.
// grid (32, 24) = 768 blocks (3x CU count — no occupancy loss) while halving
// h2 A-passes (48 -> 24). Accumulation order per output element identical.
// ---------------------------------------------------------------------------
__global__ __launch_bounds__(256) void gemm3w_kernel(
    const _Float16* __restrict__ h2, const _Float16* __restrict__ fw3h,
    const float* __restrict__ fb3, float* __restrict__ out)
{
    __shared__ _Float16 aS[64][40];
    __shared__ _Float16 wS[128][40];
    const int mb = blockIdx.x * 64, nb = blockIdx.y * 128;
    const int tid = threadIdx.x, lane = tid & 63, wq = tid >> 6;
    const int lrow = lane & 15, lhi = lane >> 4;
    f32x4 acc[8];
#pragma unroll
    for (int nt = 0; nt < 8; ++nt) acc[nt] = (f32x4){0, 0, 0, 0};

    const int sr  = tid >> 2;          // A staging: 64 rows x 32
    const int sk  = (tid & 3) * 8;
    const int sr2 = tid >> 1;          // W staging: 128 rows x 32
    const int sk2 = (tid & 1) * 16;

    for (int k0 = 0; k0 < 256; k0 += 32) {
        *(h8f16*)&aS[sr][sk] = *(const h8f16*)&h2[(long)(mb + sr) * 256 + k0 + sk];
        *(h8f16*)&wS[sr2][sk2] =
            *(const h8f16*)&fw3h[(long)(nb + sr2) * 256 + k0 + sk2];
        *(h8f16*)&wS[sr2][sk2 + 8] =
            *(const h8f16*)&fw3h[(long)(nb + sr2) * 256 + k0 + sk2 + 8];
        __syncthreads();
        const h8f16 a = *(const h8f16*)&aS[wq * 16 + lrow][lhi * 8];
#pragma unroll
        for (int nt = 0; nt < 8; ++nt) {
            const h8f16 bfr = *(const h8f16*)&wS[nt * 16 + lrow][lhi * 8];
            acc[nt] = MFMA16(a, bfr, acc[nt]);
        }
        __syncthreads();
    }

#pragma unroll
    for (int nt = 0; nt < 8; ++nt) {
        const int cc = nb + nt * 16 + lrow;
        const float bv = fb3[cc];
#pragma unroll
        for (int j = 0; j < 4; ++j) {
            const int rr = mb + wq * 16 + lhi * 4 + j;
            out[(long)rr * 3072 + cc] = acc[nt][j] + bv;
        }
    }
}

// ---------------------------------------------------------------------------
extern "C" void kernel_launch(void* const* d_in, const int* in_sizes, int n_in,
                              void* d_out, int out_size, void* d_ws, size_t ws_size,
                              hipStream_t stream)
{
    const float* x_t     = (const float*)d_in[0];
    const float* past    = (const float*)d_in[1];
    const int*   tvals   = (const int*)d_in[2];
    const float* xproj_w = (const float*)d_in[3];
    const float* xproj_b = (const float*)d_in[4];
    const float* z0_w    = (const float*)d_in[5];
    const float* z0_b    = (const float*)d_in[6];
    const float* ln_g    = (const float*)d_in[7];
    const float* ln_b    = (const float*)d_in[8];
    const float* w1      = (const float*)d_in[9];
    const float* b1      = (const float*)d_in[10];
    const float* w2      = (const float*)d_in[11];
    const float* b2      = (const float*)d_in[12];
    const float* w3      = (const float*)d_in[13];
    const float* b3      = (const float*)d_in[14];
    const float* fw1     = (const float*)d_in[15];
    const float* fb1     = (const float*)d_in[16];
    const float* fw2     = (const float*)d_in[17];
    const float* fb2     = (const float*)d_in[18];
    const float* fw3     = (const float*)d_in[19];
    const float* fb3     = (const float*)d_in[20];

    char* ws = (char*)d_ws;
    float*     zbuf = (float*)ws;                         // 1 MB   (B*128 f32)
    _Float16*  hcat = (_Float16*)(ws + (1 << 20));        // 13.63 MB
    _Float16*  h1   = (_Float16*)(ws + 15 * (1 << 20));   // 1 MB
    _Float16*  h2   = (_Float16*)(ws + 16 * (1 << 20));   // 1 MB
    _Float16*  fw1h = (_Float16*)(ws + 17 * (1 << 20));   // 1.70 MB (256x3328)
    _Float16*  fw2h = (_Float16*)(ws + 19 * (1 << 20));   // 0.13 MB (256x256)
    _Float16*  fw3h = (_Float16*)(ws + 20 * (1 << 20));   // 1.57 MB (3072x256)

    fat_kernel<<<232, 512, 0, stream>>>(past, xproj_w, xproj_b, z0_w, z0_b,
                                        ln_g, ln_b, w1, b1, w2, b2, w3, b3,
                                        x_t, tvals, fw1, fw2, fw3,
                                        zbuf, hcat, fw1h, fw2h, fw3h);

    gemm1z_kernel<<<dim3(32, 4), 256, 0, stream>>>(hcat, zbuf, fw1h, fb1, h1);

    gemm_ff<true, true><<<dim3(32, 4), 256, 0, stream>>>(h1, fw2h, fb2, h2, 2048, 256, 256);

    gemm3w_kernel<<<dim3(32, 24), 256, 0, stream>>>(h2, fw3h, fb3, (float*)d_out);
}

// Round 18
// 295.491 us; speedup vs baseline: 1.0704x; 1.0068x over previous
//
#include <hip/hip_runtime.h>
#include <math.h>

typedef _Float16 h8f16 __attribute__((ext_vector_type(8)));
typedef _Float16 h2f16 __attribute__((ext_vector_type(2)));
typedef float f32x4 __attribute__((ext_vector_type(4)));

#define MFMA16(a, b, c) __builtin_amdgcn_mfma_f32_16x16x32_f16((a), (b), (c), 0, 0, 0)

__device__ __forceinline__ float silu_f(float v) {
    return v * __builtin_amdgcn_rcpf(1.0f + __expf(-v));
}

// Bare barrier: writer-side LDS completion + s_barrier, NO vmcnt drain.
__device__ __forceinline__ void bar_lds() {
    asm volatile("s_waitcnt lgkmcnt(0)" ::: "memory");
    __builtin_amdgcn_s_barrier();
    __builtin_amdgcn_sched_barrier(0);
}

// ---------------------------------------------------------------------------
// FAT kernel, 232 blocks x 512 threads:
//   blocks 0..127   : ODE mega-kernel (v6 structure; this round: 2-way split
//                     MFMA accumulator chains in all three phases)
//   blocks 128..231 : pure-STREAMING filler (round-14 proven, verbatim)
// ---------------------------------------------------------------------------
__global__ __launch_bounds__(512, 1) void fat_kernel(
    const float* __restrict__ past,
    const float* __restrict__ xproj_w, const float* __restrict__ xproj_b,
    const float* __restrict__ z0_w, const float* __restrict__ z0_b,
    const float* __restrict__ ln_g, const float* __restrict__ ln_b,
    const float* __restrict__ w1, const float* __restrict__ b1,
    const float* __restrict__ w2, const float* __restrict__ b2,
    const float* __restrict__ w3, const float* __restrict__ b3,
    const float* __restrict__ x_t, const int* __restrict__ tvals,
    const float* __restrict__ fw1, const float* __restrict__ fw2,
    const float* __restrict__ fw3,
    float* __restrict__ zbuf, _Float16* __restrict__ hcat,
    _Float16* __restrict__ fw1h, _Float16* __restrict__ fw2h,
    _Float16* __restrict__ fw3h)
{
    __shared__ _Float16 hbuf[16][136];
    __shared__ _Float16 h1S[16][136];
    __shared__ _Float16 h2S[16][136];
    __shared__ float    pS[16][33];
    __shared__ float    x0S[16][128];
    __shared__ float    zS0[16][129];

    const int tid = threadIdx.x;

    if (blockIdx.x >= 128) {
        const int fid = blockIdx.x - 128;          // 0..103
        for (long c = fid * 512 + tid; c < 1032192; c += 104 * 512) {
            if (c < 786432) {
                const long b = c / 384, q = (c % 384) * 8;
                const float* s = x_t + b * 3072 + q;
                const f32x4 u0 = *(const f32x4*)s;
                const f32x4 u1 = *(const f32x4*)(s + 4);
                h8f16 v;
#pragma unroll
                for (int j = 0; j < 4; ++j) { v[j] = (_Float16)u0[j]; v[4 + j] = (_Float16)u1[j]; }
                *(h8f16*)&hcat[b * 3328 + q] = v;
            } else if (c < 819200) {
                const long u = c - 786432;
                const long b = u >> 4;
                const int j0 = (int)(u & 15) * 8;
                const float tv = (float)tvals[b];
                h8f16 v;
#pragma unroll
                for (int j = 0; j < 8; ++j) {
                    const int jj  = j0 + j;
                    const int idx = (jj < 64) ? jj : jj - 64;
                    const float fr = expf(-9.210340371976184f * (float)idx * (1.0f / 63.0f));
                    const float a  = tv * fr;
                    v[j] = (_Float16)((jj < 64) ? sinf(a) : cosf(a));
                }
                *(h8f16*)&hcat[b * 3328 + 3200 + j0] = v;
            } else {
                const float* src; _Float16* dst; long off;
                if (c < 925696)      { src = fw1; dst = fw1h; off = (c - 819200) * 8; }
                else if (c < 933888) { src = fw2; dst = fw2h; off = (c - 925696) * 8; }
                else                 { src = fw3; dst = fw3h; off = (c - 933888) * 8; }
                const f32x4 u0 = *(const f32x4*)(src + off);
                const f32x4 u1 = *(const f32x4*)(src + off + 4);
                h8f16 v;
#pragma unroll
                for (int j = 0; j < 4; ++j) { v[j] = (_Float16)u0[j]; v[4 + j] = (_Float16)u1[j]; }
                *(h8f16*)&dst[off] = v;
            }
        }
        return;
    }

    // ===================== ODE path =====================
    const int wid  = tid >> 6;
    const int lane = tid & 63;
    const int lrow = lane & 15;
    const int lhi  = lane >> 4;
    const int b0   = blockIdx.x * 16;
    const int nc   = wid * 16 + lrow;
    const int koff = lhi * 8;

    h8f16 w1f[4], wcf, w2f[4], w3f[4];
    float b1t, b2r, b3r;
    {
#pragma unroll
        for (int ks = 0; ks < 4; ++ks) {
            h8f16 v1, v2, v3;
#pragma unroll
            for (int j = 0; j < 8; ++j) {
                const int k = ks * 32 + koff + j;
                v1[j] = (_Float16)(w1[nc * 256 + k] * ln_g[k]);
                v2[j] = (_Float16)w2[nc * 128 + k];
                v3[j] = (_Float16)w3[nc * 128 + k];
            }
            w1f[ks] = v1; w2f[ks] = v2; w3f[ks] = v3;
        }
        float wc[8] = {0, 0, 0, 0, 0, 0, 0, 0};
        float bc = 0.0f, bb = 0.0f;
        const float* w1a = w1 + nc * 256;
        const float* w1b = w1a + 128;
#pragma unroll 4
        for (int k = 0; k < 128; ++k) {
            const float a = w1b[k];
            bc += a * xproj_b[k];
            bb += w1a[k] * ln_b[k];
            const float* xr = xproj_w + k * 32 + koff;
#pragma unroll
            for (int j = 0; j < 8; ++j) wc[j] += a * xr[j];
        }
        h8f16 v;
#pragma unroll
        for (int j = 0; j < 8; ++j) v[j] = (_Float16)wc[j];
        wcf = v;
        b1t = b1[nc] + bc + bb;
        b2r = b2[nc]; b3r = b3[nc];
    }

    pS[tid >> 5][tid & 31] = past[(long)(b0 + (tid >> 5)) * 16384 + (tid & 31)];
    __syncthreads();
    {
        const int r  = tid >> 5;
        const int c0 = (tid & 31) * 4;
#pragma unroll
        for (int cc = 0; cc < 4; ++cc) {
            const int kc = c0 + cc;
            float s = xproj_b[kc];
            const float* xr = xproj_w + kc * 32;
#pragma unroll
            for (int c = 0; c < 32; ++c) s += pS[r][c] * xr[c];
            x0S[r][kc] = s;
        }
    }
    __syncthreads();
    {
        const int nn = tid & 127;
        const int r0 = (tid >> 7) * 4;
        for (int p = 0; p < 4; ++p) {
            const int r = r0 + p;
            float s = z0_b[nn];
            const float* zr = z0_w + nn * 128;
            for (int k = 0; k < 128; ++k) s += x0S[r][k] * zr[k];
            zS0[r][nn] = s;
        }
    }
    __syncthreads();

    float zc[4], krk[4];
#pragma unroll
    for (int j = 0; j < 4; ++j) {
        zc[j] = zS0[4 * lhi + j][nc];
        hbuf[4 * lhi + j][nc] = (_Float16)zc[j];
    }

    const float DT = 1.0f / 32.0f;

    f32x4 s0a, s0b, s1a, s1b;
    auto stage = [&](int e) {
        const float pos = (float)e * 7.984375f;   // e*(511/64), exact
        const int i0 = (int)pos;
        const int i1 = (i0 < 511) ? i0 + 1 : 511;
        const float* base = past + (long)(b0 + lrow) * 16384;
        const float* p0 = base + i0 * 32 + koff;
        const float* p1 = base + i1 * 32 + koff;
        s0a = *(const f32x4*)p0; s0b = *(const f32x4*)(p0 + 4);
        s1a = *(const f32x4*)p1; s1b = *(const f32x4*)(p1 + 4);
    };
    auto blend = [&](int e) -> h8f16 {
        const float pos = (float)e * 7.984375f;
        const float w = pos - floorf(pos);
        h8f16 r;
#pragma unroll
        for (int j = 0; j < 4; ++j) {
            r[j]     = (_Float16)(s0a[j] + w * (s1a[j] - s0a[j]));
            r[4 + j] = (_Float16)(s0b[j] + w * (s1b[j] - s0b[j]));
        }
        return r;
    };

    const h2f16 one2 = {(_Float16)1.0f, (_Float16)1.0f};

    // phase A: LN-apply + layer1; accumulator split into 2 independent chains
    auto phaseA = [&](h8f16 bxc) {
        h8f16 xf[4];
#pragma unroll
        for (int ks = 0; ks < 4; ++ks)
            xf[ks] = *(const h8f16*)&hbuf[lrow][ks * 32 + koff];
        float s0 = 0.f, s1 = 0.f, q0 = 0.f, q1 = 0.f;
#pragma unroll
        for (int ks = 0; ks < 4; ++ks) {
#pragma unroll
            for (int p = 0; p < 4; ++p) {
                const h2f16 x2 = {xf[ks][2 * p], xf[ks][2 * p + 1]};
                if (p & 1) {
                    s1 = __builtin_amdgcn_fdot2(x2, one2, s1, false);
                    q1 = __builtin_amdgcn_fdot2(x2, x2, q1, false);
                } else {
                    s0 = __builtin_amdgcn_fdot2(x2, one2, s0, false);
                    q0 = __builtin_amdgcn_fdot2(x2, x2, q0, false);
                }
            }
        }
        float s = s0 + s1, q = q0 + q1;
        s += __shfl_xor(s, 16); q += __shfl_xor(q, 16);
        s += __shfl_xor(s, 32); q += __shfl_xor(q, 32);
        const float mu  = s * (1.0f / 128.0f);
        const float var = q * (1.0f / 128.0f) - mu * mu;
        const float inv = 1.0f / sqrtf(var + 1e-5f);
        const _Float16 ih = (_Float16)inv;
        const _Float16 mh = (_Float16)(-mu * inv);
        h8f16 ip, mp;
#pragma unroll
        for (int j = 0; j < 8; ++j) { ip[j] = ih; mp[j] = mh; }
        // two independent MFMA chains (depth 3 + 3 instead of 5)
        f32x4 a0 = {0, 0, 0, 0}, a1 = {0, 0, 0, 0};
        {
            const h8f16 az0 = xf[0] * ip + mp;
            const h8f16 az1 = xf[1] * ip + mp;
            const h8f16 az2 = xf[2] * ip + mp;
            const h8f16 az3 = xf[3] * ip + mp;
            a0 = MFMA16(az0, w1f[0], a0);
            a1 = MFMA16(az2, w1f[2], a1);
            a0 = MFMA16(az1, w1f[1], a0);
            a1 = MFMA16(az3, w1f[3], a1);
            a0 = MFMA16(bxc, wcf, a0);
        }
        const f32x4 acc = a0 + a1;
#pragma unroll
        for (int j = 0; j < 4; ++j)
            h1S[4 * lhi + j][nc] = (_Float16)silu_f(acc[j] + b1t);
    };
    auto phaseB = [&]() {
        f32x4 a0 = {0, 0, 0, 0}, a1 = {0, 0, 0, 0};
        const h8f16 x0 = *(const h8f16*)&h1S[lrow][0 * 32 + koff];
        const h8f16 x1 = *(const h8f16*)&h1S[lrow][1 * 32 + koff];
        const h8f16 x2 = *(const h8f16*)&h1S[lrow][2 * 32 + koff];
        const h8f16 x3 = *(const h8f16*)&h1S[lrow][3 * 32 + koff];
        a0 = MFMA16(x0, w2f[0], a0);
        a1 = MFMA16(x2, w2f[2], a1);
        a0 = MFMA16(x1, w2f[1], a0);
        a1 = MFMA16(x3, w2f[3], a1);
        const f32x4 acc = a0 + a1;
#pragma unroll
        for (int j = 0; j < 4; ++j)
            h2S[4 * lhi + j][nc] = (_Float16)silu_f(acc[j] + b2r);
    };
    auto phaseC = [&]() -> f32x4 {
        f32x4 a0 = {0, 0, 0, 0}, a1 = {0, 0, 0, 0};
        const h8f16 x0 = *(const h8f16*)&h2S[lrow][0 * 32 + koff];
        const h8f16 x1 = *(const h8f16*)&h2S[lrow][1 * 32 + koff];
        const h8f16 x2 = *(const h8f16*)&h2S[lrow][2 * 32 + koff];
        const h8f16 x3 = *(const h8f16*)&h2S[lrow][3 * 32 + koff];
        a0 = MFMA16(x0, w3f[0], a0);
        a1 = MFMA16(x2, w3f[2], a1);
        a0 = MFMA16(x1, w3f[1], a0);
        a1 = MFMA16(x3, w3f[3], a1);
        f32x4 acc = a0 + a1;
#pragma unroll
        for (int j = 0; j < 4; ++j) acc[j] += b3r;
        return acc;
    };

    stage(0);
    h8f16 bxc = blend(0);
    __syncthreads();

#pragma unroll 1
    for (int st = 0; st < 32; ++st) {
        const int e1 = 2 * st + 1, e2 = 2 * st + 2;
        phaseA(bxc);
        stage(e1);
        bar_lds();
        phaseB(); bar_lds();
        {
            const f32x4 k = phaseC();
#pragma unroll
            for (int j = 0; j < 4; ++j) {
                krk[j] = k[j];
                hbuf[4 * lhi + j][nc] = (_Float16)(zc[j] + 0.5f * DT * k[j]);
            }
        }
        bar_lds();
        bxc = blend(e1);
        phaseA(bxc); bar_lds();
        phaseB(); bar_lds();
        {
            const f32x4 k = phaseC();
#pragma unroll
            for (int j = 0; j < 4; ++j) {
                krk[j] += 2.0f * k[j];
                hbuf[4 * lhi + j][nc] = (_Float16)(zc[j] + 0.5f * DT * k[j]);
            }
        }
        bar_lds();
        phaseA(bxc);
        stage(e2);
        bar_lds();
        phaseB(); bar_lds();
        {
            const f32x4 k = phaseC();
#pragma unroll
            for (int j = 0; j < 4; ++j) {
                krk[j] += 2.0f * k[j];
                hbuf[4 * lhi + j][nc] = (_Float16)(zc[j] + DT * k[j]);
            }
        }
        bar_lds();
        bxc = blend(e2);
        phaseA(bxc); bar_lds();
        phaseB(); bar_lds();
        {
            const f32x4 k = phaseC();
#pragma unroll
            for (int j = 0; j < 4; ++j) {
                zc[j] += (DT / 6.0f) * (krk[j] + k[j]);
                hbuf[4 * lhi + j][nc] = (_Float16)zc[j];
            }
        }
        bar_lds();
    }

#pragma unroll
    for (int j = 0; j < 4; ++j)
        zbuf[(long)(b0 + 4 * lhi + j) * 128 + nc] = zc[j];
}

// ---------------------------------------------------------------------------
// gemm1z: h1 = silu([hcat_xt | cond(zbuf,f32) | hcat_temb] @ fw1h.T + fb1)
// (round-14 proven, verbatim — 128 blocks, 64x64 tile)
// ---------------------------------------------------------------------------
__global__ __launch_bounds__(256) void gemm1z_kernel(
    const _Float16* __restrict__ hcat, const float* __restrict__ cond,
    const _Float16* __restrict__ fw1h, const float* __restrict__ fb1,
    _Float16* __restrict__ h1)
{
    __shared__ _Float16 aS[64][40];
    __shared__ _Float16 wS[64][40];
    const int mb = blockIdx.x * 64, nb = blockIdx.y * 64;
    const int tid = threadIdx.x, lane = tid & 63, wq = tid >> 6;
    const int lrow = lane & 15, lhi = lane >> 4;
    f32x4 acc[4];
#pragma unroll
    for (int nt = 0; nt < 4; ++nt) acc[nt] = (f32x4){0, 0, 0, 0};

    const int sr = tid >> 2;
    const int sk = (tid & 3) * 8;

    for (int k0 = 0; k0 < 3328; k0 += 32) {
        if (k0 >= 3072 && k0 < 3200) {
            const float* s = cond + (long)(mb + sr) * 128 + (k0 - 3072) + sk;
            const f32x4 u0 = *(const f32x4*)s;
            const f32x4 u1 = *(const f32x4*)(s + 4);
            h8f16 v;
#pragma unroll
            for (int j = 0; j < 4; ++j) { v[j] = (_Float16)u0[j]; v[4 + j] = (_Float16)u1[j]; }
            *(h8f16*)&aS[sr][sk] = v;
        } else {
            *(h8f16*)&aS[sr][sk] =
                *(const h8f16*)&hcat[(long)(mb + sr) * 3328 + k0 + sk];
        }
        *(h8f16*)&wS[sr][sk] = *(const h8f16*)&fw1h[(long)(nb + sr) * 3328 + k0 + sk];
        __syncthreads();
        const h8f16 a = *(const h8f16*)&aS[wq * 16 + lrow][lhi * 8];
#pragma unroll
        for (int nt = 0; nt < 4; ++nt) {
            const h8f16 bfr = *(const h8f16*)&wS[nt * 16 + lrow][lhi * 8];
            acc[nt] = MFMA16(a, bfr, acc[nt]);
        }
        __syncthreads();
    }

#pragma unroll
    for (int nt = 0; nt < 4; ++nt) {
        const int cc = nb + nt * 16 + lrow;
        const float bv = fb1[cc];
#pragma unroll
        for (int j = 0; j < 4; ++j) {
            const int rr = mb + wq * 16 + lhi * 4 + j;
            h1[(long)rr * 256 + cc] = (_Float16)silu_f(acc[nt][j] + bv);
        }
    }
}

// ---------------------------------------------------------------------------
// Generic all-f16 MFMA GEMM (64x64): out = [silu](A @ W.T + bias)
// ---------------------------------------------------------------------------
template <bool SILU, bool OUT_F16>
__global__ __launch_bounds__(256) void gemm_ff(
    const _Float16* __restrict__ A, const _Float16* __restrict__ W,
    const float* __restrict__ bias, void* __restrict__ out,
    int M, int N, int K)
{
    __shared__ _Float16 aS[64][40];
    __shared__ _Float16 wS[64][40];
    const int mb = blockIdx.x * 64, nb = blockIdx.y * 64;
    const int tid = threadIdx.x, lane = tid & 63, wq = tid >> 6;
    const int lrow = lane & 15, lhi = lane >> 4;
    f32x4 acc[4];
#pragma unroll
    for (int nt = 0; nt < 4; ++nt) acc[nt] = (f32x4){0, 0, 0, 0};

    const int sr = tid >> 2;
    const int sk = (tid & 3) * 8;

    for (int k0 = 0; k0 < K; k0 += 32) {
        *(h8f16*)&aS[sr][sk] = *(const h8f16*)&A[(long)(mb + sr) * K + k0 + sk];
        *(h8f16*)&wS[sr][sk] = *(const h8f16*)&W[(long)(nb + sr) * K + k0 + sk];
        __syncthreads();
        const h8f16 a = *(const h8f16*)&aS[wq * 16 + lrow][lhi * 8];
#pragma unroll
        for (int nt = 0; nt < 4; ++nt) {
            const h8f16 bfr = *(const h8f16*)&wS[nt * 16 + lrow][lhi * 8];
            acc[nt] = MFMA16(a, bfr, acc[nt]);
        }
        __syncthreads();
    }

#pragma unroll
    for (int nt = 0; nt < 4; ++nt) {
        const int cc = nb + nt * 16 + lrow;
        const float bv = bias[cc];
#pragma unroll
        for (int j = 0; j < 4; ++j) {
            const int rr = mb + wq * 16 + lhi * 4 + j;
            float v = acc[nt][j] + bv;
            if (SILU) v = silu_f(v);
            if (OUT_F16) ((_Float16*)out)[(long)rr * N + cc] = (_Float16)v;
            else         ((float*)out)[(long)rr * N + cc] = v;
        }
    }
}

// ---------------------------------------------------------------------------
// gemm3w: out = h2 @ fw3h.T + fb3, tile 64(M) x 128(N), K=256. (r17, verbatim)
// ---------------------------------------------------------------------------
__global__ __launch_bounds__(256) void gemm3w_kernel(
    const _Float16* __restrict__ h2, const _Float16* __restrict__ fw3h,
    const float* __restrict__ fb3, float* __restrict__ out)
{
    __shared__ _Float16 aS[64][40];
    __shared__ _Float16 wS[128][40];
    const int mb = blockIdx.x * 64, nb = blockIdx.y * 128;
    const int tid = threadIdx.x, lane = tid & 63, wq = tid >> 6;
    const int lrow = lane & 15, lhi = lane >> 4;
    f32x4 acc[8];
#pragma unroll
    for (int nt = 0; nt < 8; ++nt) acc[nt] = (f32x4){0, 0, 0, 0};

    const int sr  = tid >> 2;
    const int sk  = (tid & 3) * 8;
    const int sr2 = tid >> 1;
    const int sk2 = (tid & 1) * 16;

    for (int k0 = 0; k0 < 256; k0 += 32) {
        *(h8f16*)&aS[sr][sk] = *(const h8f16*)&h2[(long)(mb + sr) * 256 + k0 + sk];
        *(h8f16*)&wS[sr2][sk2] =
            *(const h8f16*)&fw3h[(long)(nb + sr2) * 256 + k0 + sk2];
        *(h8f16*)&wS[sr2][sk2 + 8] =
            *(const h8f16*)&fw3h[(long)(nb + sr2) * 256 + k0 + sk2 + 8];
        __syncthreads();
        const h8f16 a = *(const h8f16*)&aS[wq * 16 + lrow][lhi * 8];
#pragma unroll
        for (int nt = 0; nt < 8; ++nt) {
            const h8f16 bfr = *(const h8f16*)&wS[nt * 16 + lrow][lhi * 8];
            acc[nt] = MFMA16(a, bfr, acc[nt]);
        }
        __syncthreads();
    }

#pragma unroll
    for (int nt = 0; nt < 8; ++nt) {
        const int cc = nb + nt * 16 + lrow;
        const float bv = fb3[cc];
#pragma unroll
        for (int j = 0; j < 4; ++j) {
            const int rr = mb + wq * 16 + lhi * 4 + j;
            out[(long)rr * 3072 + cc] = acc[nt][j] + bv;
        }
    }
}

// ---------------------------------------------------------------------------
extern "C" void kernel_launch(void* const* d_in, const int* in_sizes, int n_in,
                              void* d_out, int out_size, void* d_ws, size_t ws_size,
                              hipStream_t stream)
{
    const float* x_t     = (const float*)d_in[0];
    const float* past    = (const float*)d_in[1];
    const int*   tvals   = (const int*)d_in[2];
    const float* xproj_w = (const float*)d_in[3];
    const float* xproj_b = (const float*)d_in[4];
    const float* z0_w    = (const float*)d_in[5];
    const float* z0_b    = (const float*)d_in[6];
    const float* ln_g    = (const float*)d_in[7];
    const float* ln_b    = (const float*)d_in[8];
    const float* w1      = (const float*)d_in[9];
    const float* b1      = (const float*)d_in[10];
    const float* w2      = (const float*)d_in[11];
    const float* b2      = (const float*)d_in[12];
    const float* w3      = (const float*)d_in[13];
    const float* b3      = (const float*)d_in[14];
    const float* fw1     = (const float*)d_in[15];
    const float* fb1     = (const float*)d_in[16];
    const float* fw2     = (const float*)d_in[17];
    const float* fb2     = (const float*)d_in[18];
    const float* fw3     = (const float*)d_in[19];
    const float* fb3     = (const float*)d_in[20];

    char* ws = (char*)d_ws;
    float*     zbuf = (float*)ws;                         // 1 MB   (B*128 f32)
    _Float16*  hcat = (_Float16*)(ws + (1 << 20));        // 13.63 MB
    _Float16*  h1   = (_Float16*)(ws + 15 * (1 << 20));   // 1 MB
    _Float16*  h2   = (_Float16*)(ws + 16 * (1 << 20));   // 1 MB
    _Float16*  fw1h = (_Float16*)(ws + 17 * (1 << 20));   // 1.70 MB (256x3328)
    _Float16*  fw2h = (_Float16*)(ws + 19 * (1 << 20));   // 0.13 MB (256x256)
    _Float16*  fw3h = (_Float16*)(ws + 20 * (1 << 20));   // 1.57 MB (3072x256)

    fat_kernel<<<232, 512, 0, stream>>>(past, xproj_w, xproj_b, z0_w, z0_b,
                                        ln_g, ln_b, w1, b1, w2, b2, w3, b3,
                                        x_t, tvals, fw1, fw2, fw3,
                                        zbuf, hcat, fw1h, fw2h, fw3h);

    gemm1z_kernel<<<dim3(32, 4), 256, 0, stream>>>(hcat, zbuf, fw1h, fb1, h1);

    gemm_ff<true, true><<<dim3(32, 4), 256, 0, stream>>>(h1, fw2h, fb2, h2, 2048, 256, 256);

    gemm3w_kernel<<<dim3(32, 24), 256, 0, stream>>>(h2, fw3h, fb3, (float*)d_out);
}